// Round 1
// baseline (366.418 us; speedup 1.0000x reference)
//
#include <hip/hip_runtime.h>

// WindowAttention fused kernel for MI355X (gfx950) — v2 "register attention".
// Shapes: B_=4096 windows, N=64 tokens, DIM=128, NH=4 heads, HD=32, nW=64.
// One block per window, one wave per head. bf16 MFMA 32x32x16, fp32 accum.
//
// v2 vs v1 (334.9us, 2 blocks/CU): compute qT/kT/vT = W·X^T instead of X·W^T.
// The T-form C-layout puts the token index in lane&31, so q/k/P MFMA fragments
// are built IN REGISTERS (half-wave exchange via shfl_xor 32); S^T comes out
// with each lane owning half a softmax row (partner = lane^32) -> softmax is
// 2 shuffles instead of a 320-shuffle butterfly. q, k, P never touch LDS:
// LDS 76800 -> 35840 B (Xb + per-head vT), occupancy 2 -> 4 blocks/CU.

typedef __bf16 bf16x8 __attribute__((ext_vector_type(8)));
typedef float f32x16 __attribute__((ext_vector_type(16)));

#define MFMA32(a, b, c) __builtin_amdgcn_mfma_f32_32x32x16_bf16(a, b, c, 0, 0, 0)
#define ATT_SCALE 0.17677669529663687f  // 32^-0.5

__device__ __forceinline__ unsigned short f2bf(float f) {
  union { float fv; unsigned int u; } cv; cv.fv = f;
  unsigned int r = cv.u + 0x7FFFu + ((cv.u >> 16) & 1u);  // RNE truncate
  return (unsigned short)(r >> 16);
}

__device__ __forceinline__ unsigned pk2(float lo, float hi) {
  union { __bf16 h[2]; unsigned u; } t;
  t.h[0] = (__bf16)lo; t.h[1] = (__bf16)hi;  // compiler emits v_cvt_pk_bf16_f32
  return t.u;
}

// C-regs of the T-form hold rows d=(r&3)+8*(r>>2)+4*hl at col=lane&31.
// A/B fragments need 8 consecutive k at this lane: lower 4-group from hl'=0
// values (lanes<32), upper from hl'=1 (lanes>=32) -> exchange via shfl_xor 32.
// pairw: given pk-words of (own low 4-group pair) and (own high 4-group pair),
// produce the e01 word (wlo) and e45 word (whi) of the fragment.
__device__ __forceinline__ void pairw(float l0, float l1, float h0, float h1,
                                      int hl, unsigned &wlo, unsigned &whi) {
  unsigned lo = pk2(l0, l1);
  unsigned hi = pk2(h0, h1);
  unsigned los = (unsigned)__shfl_xor((int)lo, 32);
  unsigned his = (unsigned)__shfl_xor((int)hi, 32);
  wlo = hl ? his : lo;   // lanes>=32 take partner's hi-group pair
  whi = hl ? hi : los;   // lanes<32 take partner's lo-group pair
}

// Build one K=16 fragment slot from 8 C-reg values (local k 0..15).
__device__ __forceinline__ bf16x8 frag8(float a0, float a1, float a2, float a3,
                                        float a4, float a5, float a6, float a7,
                                        int hl) {
  union { unsigned u[4]; bf16x8 v; } r;
  pairw(a0, a1, a4, a5, hl, r.u[0], r.u[2]);
  pairw(a2, a3, a6, a7, hl, r.u[1], r.u[3]);
  return r.v;
}

#define FRAG_LO(p) frag8(p[0], p[1], p[2], p[3], p[4], p[5], p[6], p[7], hl)
#define FRAG_HI(p) frag8(p[8], p[9], p[10], p[11], p[12], p[13], p[14], p[15], hl)

// ---- pre-kernel 1: fp32 weights -> bf16 (q rows pre-scaled by ATT_SCALE) ----
__global__ __launch_bounds__(256) void convert_weights(
    const float* __restrict__ qkv_w, const float* __restrict__ proj_w,
    unsigned short* __restrict__ wq, unsigned short* __restrict__ wp) {
  int t = blockIdx.x * 256 + threadIdx.x;  // 65536 total = 49152 + 16384
  if (t < 384 * 128) {
    float v = qkv_w[t];
    if (t < 128 * 128) v *= ATT_SCALE;     // q rows
    wq[t] = f2bf(v);
  } else {
    wp[t - 384 * 128] = f2bf(proj_w[t - 384 * 128]);
  }
}

// ---- pre-kernel 2: TRANSPOSED combined bias cbT[w][h][j][i] = rel[h][i][j]+mask[w][i][j] ----
__global__ __launch_bounds__(256) void build_cb(
    const float* __restrict__ mask, const float* __restrict__ bias_table,
    float* __restrict__ cb) {
  int t = blockIdx.x * 256 + threadIdx.x;  // nW*4*4096 total
  int ij = t & 4095;
  int h = (t >> 12) & 3;
  int w = t >> 14;
  int j = ij >> 6, i = ij & 63;            // storage [j][i], value for (i,j)
  int ridx = ((i >> 3) - (j >> 3) + 7) * 15 + ((i & 7) - (j & 7) + 7);
  cb[t] = bias_table[ridx * 4 + h] + mask[(w << 12) + (i << 6) + j];
}

// ---- fused window attention ----
__global__ __launch_bounds__(256, 4) void window_attn(
    const float* __restrict__ x, const float* __restrict__ qkv_b,
    const float* __restrict__ proj_b, const unsigned short* __restrict__ wq,
    const unsigned short* __restrict__ wp, const float* __restrict__ cbT,
    float* __restrict__ out, int nW) {
  __shared__ unsigned short Xb[64][136];   // 17408 B; x bf16, reused as O
  __shared__ unsigned short Vt[4][32][72]; // 18432 B; vT[d][j] per head

  const int tid = threadIdx.x;
  const int h = tid >> 6;          // wave index == head
  const int lane = tid & 63;
  const int l31 = lane & 31;
  const int hl = lane >> 5;
  const int b = blockIdx.x;
  const int w = b % nW;

  // ---- stage x[b] (64x128 fp32) -> bf16 LDS, coalesced float4 ----
  const float* xb = x + (size_t)b * 8192;
  #pragma unroll
  for (int st = 0; st < 8; ++st) {
    int e = (st * 256 + tid) * 4;
    float4 v4 = *reinterpret_cast<const float4*>(xb + e);
    ushort4 o;
    o.x = f2bf(v4.x); o.y = f2bf(v4.y); o.z = f2bf(v4.z); o.w = f2bf(v4.w);
    *reinterpret_cast<ushort4*>(&Xb[e >> 7][e & 127]) = o;
  }
  __syncthreads();

  // ---- pass V: vT = Wv · X^T  (A = Wv rows, B = Xb token rows) ----
  {
    f32x16 av0, av1;
    #pragma unroll
    for (int q = 0; q < 16; ++q) { av0[q] = 0.0f; av1[q] = 0.0f; }
    const unsigned short* wvp = wq + (size_t)(256 + h * 32 + l31) * 128 + hl * 8;
    #pragma unroll
    for (int kt = 0; kt < 8; ++kt) {
      bf16x8 aw = *reinterpret_cast<const bf16x8*>(wvp + kt * 16);
      bf16x8 b0 = *reinterpret_cast<const bf16x8*>(&Xb[l31][kt * 16 + hl * 8]);
      bf16x8 b1 = *reinterpret_cast<const bf16x8*>(&Xb[32 + l31][kt * 16 + hl * 8]);
      av0 = MFMA32(aw, b0, av0);   // C[d][token 0..31]
      av1 = MFMA32(aw, b1, av1);   // C[d][token 32..63]
    }
    #pragma unroll
    for (int r = 0; r < 16; ++r) {
      int dr = (r & 3) + 8 * (r >> 2) + 4 * hl;
      float bv = qkv_b[256 + h * 32 + dr];
      Vt[h][dr][l31]      = f2bf(av0[r] + bv);   // vT[d][j], wave-private
      Vt[h][dr][32 + l31] = f2bf(av1[r] + bv);
    }
  }

  // ---- pass QK: qT = (scaled Wq)·X^T, kT = Wk·X^T ----
  f32x16 aq[2], ak[2];
  #pragma unroll
  for (int t2 = 0; t2 < 2; ++t2)
    #pragma unroll
    for (int q = 0; q < 16; ++q) { aq[t2][q] = 0.0f; ak[t2][q] = 0.0f; }
  {
    const unsigned short* wqp = wq + (size_t)(h * 32 + l31) * 128 + hl * 8;
    const unsigned short* wkp = wq + (size_t)(128 + h * 32 + l31) * 128 + hl * 8;
    #pragma unroll
    for (int kt = 0; kt < 8; ++kt) {
      bf16x8 b0 = *reinterpret_cast<const bf16x8*>(&Xb[l31][kt * 16 + hl * 8]);
      bf16x8 b1 = *reinterpret_cast<const bf16x8*>(&Xb[32 + l31][kt * 16 + hl * 8]);
      bf16x8 awq = *reinterpret_cast<const bf16x8*>(wqp + kt * 16);
      bf16x8 awk = *reinterpret_cast<const bf16x8*>(wkp + kt * 16);
      aq[0] = MFMA32(awq, b0, aq[0]);
      aq[1] = MFMA32(awq, b1, aq[1]);
      ak[0] = MFMA32(awk, b0, ak[0]);
      ak[1] = MFMA32(awk, b1, ak[1]);
    }
  }
  __syncthreads();  // all Xb reads done -> Xb reusable as O

  // biases (q bias scaled to match pre-scaled Wq)
  #pragma unroll
  for (int r = 0; r < 16; ++r) {
    int dr = (r & 3) + 8 * (r >> 2) + 4 * hl;
    float bq = qkv_b[h * 32 + dr] * ATT_SCALE;
    float bk = qkv_b[128 + h * 32 + dr];
    aq[0][r] += bq; aq[1][r] += bq;
    ak[0][r] += bk; ak[1][r] += bk;
  }

  // in-register q/k fragments: lane holds {q,k}[token=l31+32t][d frag]
  bf16x8 qf[2][2], kf[2][2];
  #pragma unroll
  for (int t2 = 0; t2 < 2; ++t2) {
    qf[t2][0] = FRAG_LO(aq[t2]); qf[t2][1] = FRAG_HI(aq[t2]);
    kf[t2][0] = FRAG_LO(ak[t2]); kf[t2][1] = FRAG_HI(ak[t2]);
  }

  // ---- S^T = k q^T : sacc[mt][it] holds S[i=l31+32it][j=(r&3)+8(r>>2)+4hl+32mt] ----
  f32x16 sacc[2][2];
  #pragma unroll
  for (int mt = 0; mt < 2; ++mt)
    #pragma unroll
    for (int it = 0; it < 2; ++it) {
      #pragma unroll
      for (int q = 0; q < 16; ++q) sacc[mt][it][q] = 0.0f;
      sacc[mt][it] = MFMA32(kf[mt][0], qf[it][0], sacc[mt][it]);
      sacc[mt][it] = MFMA32(kf[mt][1], qf[it][1], sacc[mt][it]);
    }

  // ---- softmax: each lane owns half of row i=l31+32it; partner = lane^32 ----
  const float* cbp = cbT + (((size_t)w * 4 + h) << 12);
  float rinv[2];
  #pragma unroll
  for (int it = 0; it < 2; ++it) {
    #pragma unroll
    for (int mt = 0; mt < 2; ++mt)
      #pragma unroll
      for (int r = 0; r < 16; ++r) {
        int jr = (r & 3) + 8 * (r >> 2) + 4 * hl + 32 * mt;
        sacc[mt][it][r] += cbp[jr * 64 + 32 * it + l31];  // cbT[j][i], coalesced
      }
    float m = sacc[0][it][0];
    #pragma unroll
    for (int mt = 0; mt < 2; ++mt)
      #pragma unroll
      for (int r = 0; r < 16; ++r) m = fmaxf(m, sacc[mt][it][r]);
    m = fmaxf(m, __shfl_xor(m, 32));
    float sum = 0.0f;
    #pragma unroll
    for (int mt = 0; mt < 2; ++mt)
      #pragma unroll
      for (int r = 0; r < 16; ++r) {
        float e = __expf(sacc[mt][it][r] - m);
        sacc[mt][it][r] = e;           // unnormalized P
        sum += e;
      }
    sum += __shfl_xor(sum, 32);
    rinv[it] = __builtin_amdgcn_rcpf(sum);
  }

  // in-register P^T fragments: pf{it}[kt] = P^T[j=16kt+8hl+e][i=l31+32it]
  bf16x8 pf0[4], pf1[4];
  pf0[0] = FRAG_LO(sacc[0][0]); pf0[1] = FRAG_HI(sacc[0][0]);
  pf0[2] = FRAG_LO(sacc[1][0]); pf0[3] = FRAG_HI(sacc[1][0]);
  pf1[0] = FRAG_LO(sacc[0][1]); pf1[1] = FRAG_HI(sacc[0][1]);
  pf1[2] = FRAG_LO(sacc[1][1]); pf1[3] = FRAG_HI(sacc[1][1]);

  // ---- O^T = vT · P^T : lane holds O[i=l31+32it][d=(r&3)+8(r>>2)+4hl] ----
  f32x16 o0, o1;
  #pragma unroll
  for (int q = 0; q < 16; ++q) { o0[q] = 0.0f; o1[q] = 0.0f; }
  #pragma unroll
  for (int kt = 0; kt < 4; ++kt) {
    bf16x8 aV = *reinterpret_cast<const bf16x8*>(&Vt[h][l31][kt * 16 + hl * 8]);
    o0 = MFMA32(aV, pf0[kt], o0);
    o1 = MFMA32(aV, pf1[kt], o1);
  }
  #pragma unroll
  for (int r = 0; r < 16; ++r) {
    int dr = (r & 3) + 8 * (r >> 2) + 4 * hl;
    Xb[l31][h * 32 + dr]      = f2bf(o0[r] * rinv[0]);  // Xb reused as O
    Xb[32 + l31][h * 32 + dr] = f2bf(o1[r] * rinv[1]);
  }
  __syncthreads();  // O (all heads) ready

  // ---- out = O proj_w^T + proj_b : wave h computes out channels [h*32, h*32+32) ----
  {
    const int c = h * 32 + l31;
    const float pb = proj_b[c];
    const unsigned short* wrow = wp + (size_t)c * 128 + hl * 8;
    bf16x8 bfr[8];
    #pragma unroll
    for (int kt = 0; kt < 8; ++kt)
      bfr[kt] = *reinterpret_cast<const bf16x8*>(wrow + kt * 16);
    float* ob = out + (size_t)b * 8192;
    #pragma unroll
    for (int mt = 0; mt < 2; ++mt) {
      f32x16 acc;
      #pragma unroll
      for (int q = 0; q < 16; ++q) acc[q] = 0.0f;
      #pragma unroll
      for (int kt = 0; kt < 8; ++kt) {
        bf16x8 a = *reinterpret_cast<const bf16x8*>(&Xb[mt * 32 + l31][kt * 16 + hl * 8]);
        acc = MFMA32(a, bfr[kt], acc);
      }
      #pragma unroll
      for (int r = 0; r < 16; ++r) {
        int row = (r & 3) + 8 * (r >> 2) + 4 * hl + mt * 32;
        ob[row * 128 + c] = acc[r] + pb;
      }
    }
  }
}

extern "C" void kernel_launch(void* const* d_in, const int* in_sizes, int n_in,
                              void* d_out, int out_size, void* d_ws, size_t ws_size,
                              hipStream_t stream) {
  const float* x          = (const float*)d_in[0];
  const float* mask       = (const float*)d_in[1];
  const float* qkv_w      = (const float*)d_in[2];
  const float* qkv_b      = (const float*)d_in[3];
  const float* proj_w     = (const float*)d_in[4];
  const float* proj_b     = (const float*)d_in[5];
  const float* bias_table = (const float*)d_in[6];
  const int B_ = in_sizes[0] / 8192;   // 4096
  const int nW = in_sizes[1] / 4096;   // 64

  // workspace carve: wq bf16 (98304 B) | wp bf16 (32768 B) | cbT fp32 (nW*4*4096*4 B)
  unsigned short* wq = (unsigned short*)d_ws;
  unsigned short* wp = wq + 384 * 128;
  float* cbuf = (float*)((char*)d_ws + 131072);

  convert_weights<<<(384 * 128 + 128 * 128) / 256, 256, 0, stream>>>(qkv_w, proj_w, wq, wp);
  build_cb<<<(nW * 4 * 4096) / 256, 256, 0, stream>>>(mask, bias_table, cbuf);
  window_attn<<<B_, 256, 0, stream>>>(x, qkv_b, proj_b, wq, wp, cbuf, (float*)d_out, nW);
}

// Round 2
// 318.928 us; speedup vs baseline: 1.1489x; 1.1489x over previous
//
#include <hip/hip_runtime.h>

// WindowAttention fused kernel for MI355X (gfx950) — v3 "register attention, fitted".
// Shapes: B_=4096 windows, N=64 tokens, DIM=128, NH=4 heads, HD=32, nW=64.
// One block per window, one wave per head. bf16 MFMA 32x32x16, fp32 accum.
//
// v3 vs v2 (203us/dispatch): v2's __launch_bounds__(256,4) capped regs at 128
// while peak live state was ~200 -> scratch spills on the critical path
// (VGPR_Count 52, all pipes idle). v3 splits the S/softmax/PV phase by
// token-half (it=0,1) so peak live regs ~145, uses (256,3) (cap 170, no
// spill, 3 blocks/CU), folds the combined bias into the S-MFMA C-input
// (deletes 64 VALU adds, hoists the 64 bias loads off the softmax path),
// and tree-shapes the 32-wide softmax max/sum reductions.

typedef __bf16 bf16x8 __attribute__((ext_vector_type(8)));
typedef float f32x16 __attribute__((ext_vector_type(16)));

#define MFMA32(a, b, c) __builtin_amdgcn_mfma_f32_32x32x16_bf16(a, b, c, 0, 0, 0)
#define ATT_SCALE 0.17677669529663687f  // 32^-0.5

__device__ __forceinline__ unsigned short f2bf(float f) {
  union { float fv; unsigned int u; } cv; cv.fv = f;
  unsigned int r = cv.u + 0x7FFFu + ((cv.u >> 16) & 1u);  // RNE truncate
  return (unsigned short)(r >> 16);
}

__device__ __forceinline__ unsigned pk2(float lo, float hi) {
  union { __bf16 h[2]; unsigned u; } t;
  t.h[0] = (__bf16)lo; t.h[1] = (__bf16)hi;  // compiler emits v_cvt_pk_bf16_f32
  return t.u;
}

// C-regs of the T-form hold rows d=(r&3)+8*(r>>2)+4*hl at col=lane&31.
// A/B fragments need 8 consecutive k at this lane: lower 4-group from hl'=0
// values (lanes<32), upper from hl'=1 (lanes>=32) -> exchange via shfl_xor 32.
__device__ __forceinline__ void pairw(float l0, float l1, float h0, float h1,
                                      int hl, unsigned &wlo, unsigned &whi) {
  unsigned lo = pk2(l0, l1);
  unsigned hi = pk2(h0, h1);
  unsigned los = (unsigned)__shfl_xor((int)lo, 32);
  unsigned his = (unsigned)__shfl_xor((int)hi, 32);
  wlo = hl ? his : lo;   // lanes>=32 take partner's hi-group pair
  whi = hl ? hi : los;   // lanes<32 take partner's lo-group pair
}

// Build one K=16 fragment slot from 8 C-reg values (local k 0..15).
__device__ __forceinline__ bf16x8 frag8(float a0, float a1, float a2, float a3,
                                        float a4, float a5, float a6, float a7,
                                        int hl) {
  union { unsigned u[4]; bf16x8 v; } r;
  pairw(a0, a1, a4, a5, hl, r.u[0], r.u[2]);
  pairw(a2, a3, a6, a7, hl, r.u[1], r.u[3]);
  return r.v;
}

#define FRAG_LO(p) frag8(p[0], p[1], p[2], p[3], p[4], p[5], p[6], p[7], hl)
#define FRAG_HI(p) frag8(p[8], p[9], p[10], p[11], p[12], p[13], p[14], p[15], hl)

// ---- pre-kernel 1: fp32 weights -> bf16 (q rows pre-scaled by ATT_SCALE) ----
__global__ __launch_bounds__(256) void convert_weights(
    const float* __restrict__ qkv_w, const float* __restrict__ proj_w,
    unsigned short* __restrict__ wq, unsigned short* __restrict__ wp) {
  int t = blockIdx.x * 256 + threadIdx.x;  // 65536 total = 49152 + 16384
  if (t < 384 * 128) {
    float v = qkv_w[t];
    if (t < 128 * 128) v *= ATT_SCALE;     // q rows
    wq[t] = f2bf(v);
  } else {
    wp[t - 384 * 128] = f2bf(proj_w[t - 384 * 128]);
  }
}

// ---- pre-kernel 2: TRANSPOSED combined bias cbT[w][h][j][i] = rel[h][i][j]+mask[w][i][j] ----
__global__ __launch_bounds__(256) void build_cb(
    const float* __restrict__ mask, const float* __restrict__ bias_table,
    float* __restrict__ cb) {
  int t = blockIdx.x * 256 + threadIdx.x;  // nW*4*4096 total
  int ij = t & 4095;
  int h = (t >> 12) & 3;
  int w = t >> 14;
  int j = ij >> 6, i = ij & 63;            // storage [j][i], value for (i,j)
  int ridx = ((i >> 3) - (j >> 3) + 7) * 15 + ((i & 7) - (j & 7) + 7);
  cb[t] = bias_table[ridx * 4 + h] + mask[(w << 12) + (i << 6) + j];
}

// ---- fused window attention ----
__global__ __launch_bounds__(256, 3) void window_attn(
    const float* __restrict__ x, const float* __restrict__ qkv_b,
    const float* __restrict__ proj_b, const unsigned short* __restrict__ wq,
    const unsigned short* __restrict__ wp, const float* __restrict__ cbT,
    float* __restrict__ out, int nW) {
  __shared__ unsigned short Xb[64][136];   // 17408 B; x bf16, reused as O
  __shared__ unsigned short Vt[4][32][72]; // 18432 B; vT[d][j] per head

  const int tid = threadIdx.x;
  const int h = tid >> 6;          // wave index == head
  const int lane = tid & 63;
  const int l31 = lane & 31;
  const int hl = lane >> 5;
  const int b = blockIdx.x;
  const int w = b % nW;

  // ---- stage x[b] (64x128 fp32) -> bf16 LDS, coalesced float4 ----
  const float* xb = x + (size_t)b * 8192;
  #pragma unroll
  for (int st = 0; st < 8; ++st) {
    int e = (st * 256 + tid) * 4;
    float4 v4 = *reinterpret_cast<const float4*>(xb + e);
    ushort4 o;
    o.x = f2bf(v4.x); o.y = f2bf(v4.y); o.z = f2bf(v4.z); o.w = f2bf(v4.w);
    *reinterpret_cast<ushort4*>(&Xb[e >> 7][e & 127]) = o;
  }
  __syncthreads();

  // ---- pass V: vT = Wv · X^T  (A = Wv rows, B = Xb token rows) ----
  {
    f32x16 av0, av1;
    #pragma unroll
    for (int q = 0; q < 16; ++q) { av0[q] = 0.0f; av1[q] = 0.0f; }
    const unsigned short* wvp = wq + (size_t)(256 + h * 32 + l31) * 128 + hl * 8;
    #pragma unroll
    for (int kt = 0; kt < 8; ++kt) {
      bf16x8 aw = *reinterpret_cast<const bf16x8*>(wvp + kt * 16);
      bf16x8 b0 = *reinterpret_cast<const bf16x8*>(&Xb[l31][kt * 16 + hl * 8]);
      bf16x8 b1 = *reinterpret_cast<const bf16x8*>(&Xb[32 + l31][kt * 16 + hl * 8]);
      av0 = MFMA32(aw, b0, av0);   // C[d][token 0..31]
      av1 = MFMA32(aw, b1, av1);   // C[d][token 32..63]
    }
    #pragma unroll
    for (int r = 0; r < 16; ++r) {
      int dr = (r & 3) + 8 * (r >> 2) + 4 * hl;
      float bv = qkv_b[256 + h * 32 + dr];
      Vt[h][dr][l31]      = f2bf(av0[r] + bv);   // vT[d][j], wave-private
      Vt[h][dr][32 + l31] = f2bf(av1[r] + bv);
    }
  }

  // ---- pass QK: qT = (scaled Wq)·X^T, kT = Wk·X^T ----
  bf16x8 qf[2][2], kf[2][2];
  {
    f32x16 aq[2], ak[2];
    #pragma unroll
    for (int t2 = 0; t2 < 2; ++t2)
      #pragma unroll
      for (int q = 0; q < 16; ++q) { aq[t2][q] = 0.0f; ak[t2][q] = 0.0f; }
    const unsigned short* wqp = wq + (size_t)(h * 32 + l31) * 128 + hl * 8;
    const unsigned short* wkp = wq + (size_t)(128 + h * 32 + l31) * 128 + hl * 8;
    #pragma unroll
    for (int kt = 0; kt < 8; ++kt) {
      bf16x8 b0 = *reinterpret_cast<const bf16x8*>(&Xb[l31][kt * 16 + hl * 8]);
      bf16x8 b1 = *reinterpret_cast<const bf16x8*>(&Xb[32 + l31][kt * 16 + hl * 8]);
      bf16x8 awq = *reinterpret_cast<const bf16x8*>(wqp + kt * 16);
      bf16x8 awk = *reinterpret_cast<const bf16x8*>(wkp + kt * 16);
      aq[0] = MFMA32(awq, b0, aq[0]);
      aq[1] = MFMA32(awq, b1, aq[1]);
      ak[0] = MFMA32(awk, b0, ak[0]);
      ak[1] = MFMA32(awk, b1, ak[1]);
    }
    __syncthreads();  // all Xb reads done -> Xb reusable as O

    // biases (q bias scaled to match pre-scaled Wq)
    #pragma unroll
    for (int r = 0; r < 16; ++r) {
      int dr = (r & 3) + 8 * (r >> 2) + 4 * hl;
      float bq = qkv_b[h * 32 + dr] * ATT_SCALE;
      float bk = qkv_b[128 + h * 32 + dr];
      aq[0][r] += bq; aq[1][r] += bq;
      ak[0][r] += bk; ak[1][r] += bk;
    }

    // in-register q/k fragments (kf first so ak dies before qf build peaks)
    #pragma unroll
    for (int t2 = 0; t2 < 2; ++t2) {
      kf[t2][0] = FRAG_LO(ak[t2]); kf[t2][1] = FRAG_HI(ak[t2]);
    }
    #pragma unroll
    for (int t2 = 0; t2 < 2; ++t2) {
      qf[t2][0] = FRAG_LO(aq[t2]); qf[t2][1] = FRAG_HI(aq[t2]);
    }
  }

  // ---- attention, split by token half it: rows i = l31 + 32*it ----
  const float* cbp = cbT + (((size_t)w * 4 + h) << 12);
  #pragma unroll
  for (int it = 0; it < 2; ++it) {
    // S^T = k q^T with C initialized to combined bias (cbT[j][i], coalesced)
    f32x16 s[2];
    #pragma unroll
    for (int mt = 0; mt < 2; ++mt)
      #pragma unroll
      for (int r = 0; r < 16; ++r) {
        int jr = (r & 3) + 8 * (r >> 2) + 4 * hl + 32 * mt;
        s[mt][r] = cbp[jr * 64 + 32 * it + l31];
      }
    #pragma unroll
    for (int mt = 0; mt < 2; ++mt) {
      s[mt] = MFMA32(kf[mt][0], qf[it][0], s[mt]);
      s[mt] = MFMA32(kf[mt][1], qf[it][1], s[mt]);
    }

    // softmax over row i (this lane + partner lane^32 hold the 64 j's)
    float mx[8];
    #pragma unroll
    for (int r = 0; r < 8; ++r)
      mx[r] = fmaxf(fmaxf(s[0][r], s[0][r + 8]), fmaxf(s[1][r], s[1][r + 8]));
    mx[0] = fmaxf(mx[0], mx[4]); mx[1] = fmaxf(mx[1], mx[5]);
    mx[2] = fmaxf(mx[2], mx[6]); mx[3] = fmaxf(mx[3], mx[7]);
    float m = fmaxf(fmaxf(mx[0], mx[1]), fmaxf(mx[2], mx[3]));
    m = fmaxf(m, __shfl_xor(m, 32));
    #pragma unroll
    for (int mt = 0; mt < 2; ++mt)
      #pragma unroll
      for (int r = 0; r < 16; ++r)
        s[mt][r] = __expf(s[mt][r] - m);        // unnormalized P
    float sm[8];
    #pragma unroll
    for (int r = 0; r < 8; ++r)
      sm[r] = (s[0][r] + s[0][r + 8]) + (s[1][r] + s[1][r + 8]);
    sm[0] += sm[4]; sm[1] += sm[5]; sm[2] += sm[6]; sm[3] += sm[7];
    float sum = (sm[0] + sm[1]) + (sm[2] + sm[3]);
    sum += __shfl_xor(sum, 32);
    const float rinv = __builtin_amdgcn_rcpf(sum);

    // in-register P^T fragments: pf[kt] = P^T[j=16kt+8hl+e][i=l31+32it]
    bf16x8 pf[4];
    pf[0] = FRAG_LO(s[0]); pf[1] = FRAG_HI(s[0]);
    pf[2] = FRAG_LO(s[1]); pf[3] = FRAG_HI(s[1]);

    // O^T = vT · P^T : lane holds O[i=l31+32it][d=(r&3)+8(r>>2)+4hl]
    f32x16 o;
    #pragma unroll
    for (int q = 0; q < 16; ++q) o[q] = 0.0f;
    #pragma unroll
    for (int kt = 0; kt < 4; ++kt) {
      bf16x8 aV = *reinterpret_cast<const bf16x8*>(&Vt[h][l31][kt * 16 + hl * 8]);
      o = MFMA32(aV, pf[kt], o);
    }
    #pragma unroll
    for (int r = 0; r < 16; ++r) {
      int dr = (r & 3) + 8 * (r >> 2) + 4 * hl;
      Xb[32 * it + l31][h * 32 + dr] = f2bf(o[r] * rinv);  // Xb reused as O
    }
  }
  __syncthreads();  // O (all heads) ready

  // ---- out = O proj_w^T + proj_b : wave h computes out channels [h*32, h*32+32) ----
  {
    const int c = h * 32 + l31;
    const float pb = proj_b[c];
    const unsigned short* wrow = wp + (size_t)c * 128 + hl * 8;
    bf16x8 bfr[8];
    #pragma unroll
    for (int kt = 0; kt < 8; ++kt)
      bfr[kt] = *reinterpret_cast<const bf16x8*>(wrow + kt * 16);
    float* ob = out + (size_t)b * 8192;
    #pragma unroll
    for (int mt = 0; mt < 2; ++mt) {
      f32x16 acc;
      #pragma unroll
      for (int q = 0; q < 16; ++q) acc[q] = 0.0f;
      #pragma unroll
      for (int kt = 0; kt < 8; ++kt) {
        bf16x8 a = *reinterpret_cast<const bf16x8*>(&Xb[mt * 32 + l31][kt * 16 + hl * 8]);
        acc = MFMA32(a, bfr[kt], acc);
      }
      #pragma unroll
      for (int r = 0; r < 16; ++r) {
        int row = (r & 3) + 8 * (r >> 2) + 4 * hl + mt * 32;
        ob[row * 128 + c] = acc[r] + pb;
      }
    }
  }
}

extern "C" void kernel_launch(void* const* d_in, const int* in_sizes, int n_in,
                              void* d_out, int out_size, void* d_ws, size_t ws_size,
                              hipStream_t stream) {
  const float* x          = (const float*)d_in[0];
  const float* mask       = (const float*)d_in[1];
  const float* qkv_w      = (const float*)d_in[2];
  const float* qkv_b      = (const float*)d_in[3];
  const float* proj_w     = (const float*)d_in[4];
  const float* proj_b     = (const float*)d_in[5];
  const float* bias_table = (const float*)d_in[6];
  const int B_ = in_sizes[0] / 8192;   // 4096
  const int nW = in_sizes[1] / 4096;   // 64

  // workspace carve: wq bf16 (98304 B) | wp bf16 (32768 B) | cbT fp32 (nW*4*4096*4 B)
  unsigned short* wq = (unsigned short*)d_ws;
  unsigned short* wp = wq + 384 * 128;
  float* cbuf = (float*)((char*)d_ws + 131072);

  convert_weights<<<(384 * 128 + 128 * 128) / 256, 256, 0, stream>>>(qkv_w, proj_w, wq, wp);
  build_cb<<<(nW * 4 * 4096) / 256, 256, 0, stream>>>(mask, bias_table, cbuf);
  window_attn<<<B_, 256, 0, stream>>>(x, qkv_b, proj_b, wq, wp, cbuf, (float*)d_out, nW);
}

// Round 3
// 302.540 us; speedup vs baseline: 1.2111x; 1.0542x over previous
//
#include <hip/hip_runtime.h>

// WindowAttention fused kernel for MI355X (gfx950) — v4.
// Shapes: B_=4096 windows, N=64 tokens, DIM=128, NH=4 heads, HD=32, nW=64.
// One block per window, one wave per head. bf16 MFMA 32x32x16, fp32 accum.
//
// v4 vs v3 (dispatch 155us, bench 319us): the ~164us gap between dispatch and
// bench wall was convert_weights + build_cb (4MB cb write, 64x-overfetch mask
// reads) + a launch gap. v4 fuses all pre-work into ONE tiny kernel (144
// blocks): LDS-transposed maskT (1MB), relT (64KB), vectorized weight
// convert. window_attn C-inits S from maskT+relT (bit-identical fp32 add,
// now L1/L2-hot: 1.06MB total vs 4MB borderline-L2 cb). Also gives O its own
// LDS buffer (53248B total, still 3 blocks/CU) removing one full-block
// barrier between QK and attention phases.

typedef __bf16 bf16x8 __attribute__((ext_vector_type(8)));
typedef float f32x16 __attribute__((ext_vector_type(16)));

#define MFMA32(a, b, c) __builtin_amdgcn_mfma_f32_32x32x16_bf16(a, b, c, 0, 0, 0)
#define ATT_SCALE 0.17677669529663687f  // 32^-0.5

__device__ __forceinline__ unsigned short f2bf(float f) {
  union { float fv; unsigned int u; } cv; cv.fv = f;
  unsigned int r = cv.u + 0x7FFFu + ((cv.u >> 16) & 1u);  // RNE truncate
  return (unsigned short)(r >> 16);
}

__device__ __forceinline__ unsigned pk2(float lo, float hi) {
  union { __bf16 h[2]; unsigned u; } t;
  t.h[0] = (__bf16)lo; t.h[1] = (__bf16)hi;  // compiler emits v_cvt_pk_bf16_f32
  return t.u;
}

// C-regs of the T-form hold rows d=(r&3)+8*(r>>2)+4*hl at col=lane&31.
// A/B fragments need 8 consecutive k at this lane: lower 4-group from hl'=0
// values (lanes<32), upper from hl'=1 (lanes>=32) -> exchange via shfl_xor 32.
__device__ __forceinline__ void pairw(float l0, float l1, float h0, float h1,
                                      int hl, unsigned &wlo, unsigned &whi) {
  unsigned lo = pk2(l0, l1);
  unsigned hi = pk2(h0, h1);
  unsigned los = (unsigned)__shfl_xor((int)lo, 32);
  unsigned his = (unsigned)__shfl_xor((int)hi, 32);
  wlo = hl ? his : lo;   // lanes>=32 take partner's hi-group pair
  whi = hl ? hi : los;   // lanes<32 take partner's lo-group pair
}

// Build one K=16 fragment slot from 8 C-reg values (local k 0..15).
__device__ __forceinline__ bf16x8 frag8(float a0, float a1, float a2, float a3,
                                        float a4, float a5, float a6, float a7,
                                        int hl) {
  union { unsigned u[4]; bf16x8 v; } r;
  pairw(a0, a1, a4, a5, hl, r.u[0], r.u[2]);
  pairw(a2, a3, a6, a7, hl, r.u[1], r.u[3]);
  return r.v;
}

#define FRAG_LO(p) frag8(p[0], p[1], p[2], p[3], p[4], p[5], p[6], p[7], hl)
#define FRAG_HI(p) frag8(p[8], p[9], p[10], p[11], p[12], p[13], p[14], p[15], hl)

// ---- fused pre-kernel: maskT transpose + relT build + weight convert ----
// grid = 144 blocks x 256:
//   blocks [0,64): maskT[w][j][i] = mask[w][i][j]   (LDS tile transpose)
//   blocks [64,80): relT[h][j*64+i] = bias_table[ridx(i,j)*4+h]
//   blocks [80,144): wq/wp bf16 convert (float4 vectorized; q rows pre-scaled)
__global__ __launch_bounds__(256) void prep(
    const float* __restrict__ mask, const float* __restrict__ bias_table,
    const float* __restrict__ qkv_w, const float* __restrict__ proj_w,
    float* __restrict__ maskT, float* __restrict__ relT,
    unsigned short* __restrict__ wq, unsigned short* __restrict__ wp) {
  const int blk = blockIdx.x;
  const int tid = threadIdx.x;
  if (blk < 64) {
    __shared__ float T[64][65];
    const float* mp = mask + (size_t)blk * 4096;
    #pragma unroll
    for (int rr = 0; rr < 16; ++rr) {
      int e = rr * 256 + tid;              // e = i*64 + j
      T[e >> 6][e & 63] = mp[e];           // coalesced read
    }
    __syncthreads();
    float* op = maskT + (size_t)blk * 4096;
    #pragma unroll
    for (int rr = 0; rr < 16; ++rr) {
      int e = rr * 256 + tid;              // e = j*64 + i
      op[e] = T[e & 63][e >> 6];           // stride-65 LDS read: conflict-free
    }
  } else if (blk < 80) {
    int t0 = (blk - 64) * 256 + tid;       // 0..4095
    #pragma unroll
    for (int u = 0; u < 4; ++u) {
      int t = u * 4096 + t0;               // coalesced over relT
      int ji = t & 4095;
      int h = t >> 12;
      int j = ji >> 6, i = ji & 63;
      int ridx = ((i >> 3) - (j >> 3) + 7) * 15 + ((i & 7) - (j & 7) + 7);
      relT[t] = bias_table[ridx * 4 + h];
    }
  } else {
    int t = ((blk - 80) * 256 + tid) * 4;  // 4 floats per thread
    if (t < 49152) {
      float4 v = *reinterpret_cast<const float4*>(qkv_w + t);
      float sc = (t < 16384) ? ATT_SCALE : 1.0f;   // q rows pre-scaled
      ushort4 o;
      o.x = f2bf(v.x * sc); o.y = f2bf(v.y * sc);
      o.z = f2bf(v.z * sc); o.w = f2bf(v.w * sc);
      *reinterpret_cast<ushort4*>(wq + t) = o;
    } else {
      int tp = t - 49152;
      float4 v = *reinterpret_cast<const float4*>(proj_w + tp);
      ushort4 o;
      o.x = f2bf(v.x); o.y = f2bf(v.y); o.z = f2bf(v.z); o.w = f2bf(v.w);
      *reinterpret_cast<ushort4*>(wp + tp) = o;
    }
  }
}

// ---- fused window attention ----
__global__ __launch_bounds__(256, 3) void window_attn(
    const float* __restrict__ x, const float* __restrict__ qkv_b,
    const float* __restrict__ proj_b, const unsigned short* __restrict__ wq,
    const unsigned short* __restrict__ wp, const float* __restrict__ maskT,
    const float* __restrict__ relT, float* __restrict__ out, int nW) {
  __shared__ unsigned short Xb[64][136];   // 17408 B; x bf16
  __shared__ unsigned short Vt[4][32][72]; // 18432 B; vT[d][j] per head
  __shared__ unsigned short Ob[64][136];   // 17408 B; attention output O

  const int tid = threadIdx.x;
  const int h = tid >> 6;          // wave index == head
  const int lane = tid & 63;
  const int l31 = lane & 31;
  const int hl = lane >> 5;
  const int b = blockIdx.x;
  const int w = b % nW;

  // ---- stage x[b] (64x128 fp32) -> bf16 LDS, coalesced float4 ----
  const float* xb = x + (size_t)b * 8192;
  #pragma unroll
  for (int st = 0; st < 8; ++st) {
    int e = (st * 256 + tid) * 4;
    float4 v4 = *reinterpret_cast<const float4*>(xb + e);
    ushort4 o;
    o.x = f2bf(v4.x); o.y = f2bf(v4.y); o.z = f2bf(v4.z); o.w = f2bf(v4.w);
    *reinterpret_cast<ushort4*>(&Xb[e >> 7][e & 127]) = o;
  }
  __syncthreads();

  // ---- pass V: vT = Wv · X^T  (A = Wv rows, B = Xb token rows) ----
  {
    f32x16 av0, av1;
    #pragma unroll
    for (int q = 0; q < 16; ++q) { av0[q] = 0.0f; av1[q] = 0.0f; }
    const unsigned short* wvp = wq + (size_t)(256 + h * 32 + l31) * 128 + hl * 8;
    #pragma unroll
    for (int kt = 0; kt < 8; ++kt) {
      bf16x8 aw = *reinterpret_cast<const bf16x8*>(wvp + kt * 16);
      bf16x8 b0 = *reinterpret_cast<const bf16x8*>(&Xb[l31][kt * 16 + hl * 8]);
      bf16x8 b1 = *reinterpret_cast<const bf16x8*>(&Xb[32 + l31][kt * 16 + hl * 8]);
      av0 = MFMA32(aw, b0, av0);   // C[d][token 0..31]
      av1 = MFMA32(aw, b1, av1);   // C[d][token 32..63]
    }
    #pragma unroll
    for (int r = 0; r < 16; ++r) {
      int dr = (r & 3) + 8 * (r >> 2) + 4 * hl;
      float bv = qkv_b[256 + h * 32 + dr];
      Vt[h][dr][l31]      = f2bf(av0[r] + bv);   // vT[d][j], wave-private
      Vt[h][dr][32 + l31] = f2bf(av1[r] + bv);
    }
  }

  // ---- pass QK: qT = (scaled Wq)·X^T, kT = Wk·X^T ----
  bf16x8 qf[2][2], kf[2][2];
  {
    f32x16 aq[2], ak[2];
    #pragma unroll
    for (int t2 = 0; t2 < 2; ++t2)
      #pragma unroll
      for (int q = 0; q < 16; ++q) { aq[t2][q] = 0.0f; ak[t2][q] = 0.0f; }
    const unsigned short* wqp = wq + (size_t)(h * 32 + l31) * 128 + hl * 8;
    const unsigned short* wkp = wq + (size_t)(128 + h * 32 + l31) * 128 + hl * 8;
    #pragma unroll
    for (int kt = 0; kt < 8; ++kt) {
      bf16x8 b0 = *reinterpret_cast<const bf16x8*>(&Xb[l31][kt * 16 + hl * 8]);
      bf16x8 b1 = *reinterpret_cast<const bf16x8*>(&Xb[32 + l31][kt * 16 + hl * 8]);
      bf16x8 awq = *reinterpret_cast<const bf16x8*>(wqp + kt * 16);
      bf16x8 awk = *reinterpret_cast<const bf16x8*>(wkp + kt * 16);
      aq[0] = MFMA32(awq, b0, aq[0]);
      aq[1] = MFMA32(awq, b1, aq[1]);
      ak[0] = MFMA32(awk, b0, ak[0]);
      ak[1] = MFMA32(awk, b1, ak[1]);
    }

    // biases (q bias scaled to match pre-scaled Wq)
    #pragma unroll
    for (int r = 0; r < 16; ++r) {
      int dr = (r & 3) + 8 * (r >> 2) + 4 * hl;
      float bq = qkv_b[h * 32 + dr] * ATT_SCALE;
      float bk = qkv_b[128 + h * 32 + dr];
      aq[0][r] += bq; aq[1][r] += bq;
      ak[0][r] += bk; ak[1][r] += bk;
    }

    // in-register q/k fragments (kf first so ak dies before qf build peaks)
    #pragma unroll
    for (int t2 = 0; t2 < 2; ++t2) {
      kf[t2][0] = FRAG_LO(ak[t2]); kf[t2][1] = FRAG_HI(ak[t2]);
    }
    #pragma unroll
    for (int t2 = 0; t2 < 2; ++t2) {
      qf[t2][0] = FRAG_LO(aq[t2]); qf[t2][1] = FRAG_HI(aq[t2]);
    }
  }

  // ---- attention, split by token half it: rows i = l31 + 32*it ----
  const float* mkp = maskT + ((size_t)w << 12);  // maskT[w][j][i], L2-hot (1MB)
  const float* rlp = relT + ((size_t)h << 12);   // relT[h][j][i], L1-hot (16KB/wave)
  #pragma unroll
  for (int it = 0; it < 2; ++it) {
    // S^T = k q^T with C initialized to combined bias (coalesced [j][i] reads)
    f32x16 s[2];
    #pragma unroll
    for (int mt = 0; mt < 2; ++mt)
      #pragma unroll
      for (int r = 0; r < 16; ++r) {
        int off = ((r & 3) + 8 * (r >> 2) + 4 * hl + 32 * mt) * 64 + 32 * it + l31;
        s[mt][r] = mkp[off] + rlp[off];
      }
    #pragma unroll
    for (int mt = 0; mt < 2; ++mt) {
      s[mt] = MFMA32(kf[mt][0], qf[it][0], s[mt]);
      s[mt] = MFMA32(kf[mt][1], qf[it][1], s[mt]);
    }

    // softmax over row i (this lane + partner lane^32 hold the 64 j's)
    float mx[8];
    #pragma unroll
    for (int r = 0; r < 8; ++r)
      mx[r] = fmaxf(fmaxf(s[0][r], s[0][r + 8]), fmaxf(s[1][r], s[1][r + 8]));
    mx[0] = fmaxf(mx[0], mx[4]); mx[1] = fmaxf(mx[1], mx[5]);
    mx[2] = fmaxf(mx[2], mx[6]); mx[3] = fmaxf(mx[3], mx[7]);
    float m = fmaxf(fmaxf(mx[0], mx[1]), fmaxf(mx[2], mx[3]));
    m = fmaxf(m, __shfl_xor(m, 32));
    #pragma unroll
    for (int mt = 0; mt < 2; ++mt)
      #pragma unroll
      for (int r = 0; r < 16; ++r)
        s[mt][r] = __expf(s[mt][r] - m);        // unnormalized P
    float sm[8];
    #pragma unroll
    for (int r = 0; r < 8; ++r)
      sm[r] = (s[0][r] + s[0][r + 8]) + (s[1][r] + s[1][r + 8]);
    sm[0] += sm[4]; sm[1] += sm[5]; sm[2] += sm[6]; sm[3] += sm[7];
    float sum = (sm[0] + sm[1]) + (sm[2] + sm[3]);
    sum += __shfl_xor(sum, 32);
    const float rinv = __builtin_amdgcn_rcpf(sum);

    // in-register P^T fragments: pf[kt] = P^T[j=16kt+8hl+e][i=l31+32it]
    bf16x8 pf[4];
    pf[0] = FRAG_LO(s[0]); pf[1] = FRAG_HI(s[0]);
    pf[2] = FRAG_LO(s[1]); pf[3] = FRAG_HI(s[1]);

    // O^T = vT · P^T : lane holds O[i=l31+32it][d=(r&3)+8(r>>2)+4hl]
    f32x16 o;
    #pragma unroll
    for (int q = 0; q < 16; ++q) o[q] = 0.0f;
    #pragma unroll
    for (int kt = 0; kt < 4; ++kt) {
      bf16x8 aV = *reinterpret_cast<const bf16x8*>(&Vt[h][l31][kt * 16 + hl * 8]);
      o = MFMA32(aV, pf[kt], o);
    }
    #pragma unroll
    for (int r = 0; r < 16; ++r) {
      int dr = (r & 3) + 8 * (r >> 2) + 4 * hl;
      Ob[32 * it + l31][h * 32 + dr] = f2bf(o[r] * rinv);
    }
  }
  __syncthreads();  // O (all heads) ready

  // ---- out = O proj_w^T + proj_b : wave h computes out channels [h*32, h*32+32) ----
  {
    const int c = h * 32 + l31;
    const float pb = proj_b[c];
    const unsigned short* wrow = wp + (size_t)c * 128 + hl * 8;
    bf16x8 bfr[8];
    #pragma unroll
    for (int kt = 0; kt < 8; ++kt)
      bfr[kt] = *reinterpret_cast<const bf16x8*>(wrow + kt * 16);
    float* ob = out + (size_t)b * 8192;
    #pragma unroll
    for (int mt = 0; mt < 2; ++mt) {
      f32x16 acc;
      #pragma unroll
      for (int q = 0; q < 16; ++q) acc[q] = 0.0f;
      #pragma unroll
      for (int kt = 0; kt < 8; ++kt) {
        bf16x8 a = *reinterpret_cast<const bf16x8*>(&Ob[mt * 32 + l31][kt * 16 + hl * 8]);
        acc = MFMA32(a, bfr[kt], acc);
      }
      #pragma unroll
      for (int r = 0; r < 16; ++r) {
        int row = (r & 3) + 8 * (r >> 2) + 4 * hl + mt * 32;
        ob[row * 128 + c] = acc[r] + pb;
      }
    }
  }
}

extern "C" void kernel_launch(void* const* d_in, const int* in_sizes, int n_in,
                              void* d_out, int out_size, void* d_ws, size_t ws_size,
                              hipStream_t stream) {
  const float* x          = (const float*)d_in[0];
  const float* mask       = (const float*)d_in[1];
  const float* qkv_w      = (const float*)d_in[2];
  const float* qkv_b      = (const float*)d_in[3];
  const float* proj_w     = (const float*)d_in[4];
  const float* proj_b     = (const float*)d_in[5];
  const float* bias_table = (const float*)d_in[6];
  const int B_ = in_sizes[0] / 8192;   // 4096
  const int nW = in_sizes[1] / 4096;   // 64

  // workspace carve: wq bf16 (98304) | wp bf16 (32768) | maskT fp32 (1MB) | relT fp32 (64KB)
  unsigned short* wq = (unsigned short*)d_ws;
  unsigned short* wp = wq + 384 * 128;
  float* maskT = (float*)((char*)d_ws + 131072);
  float* relT  = (float*)((char*)d_ws + 131072 + (size_t)nW * 4096 * 4);

  prep<<<144, 256, 0, stream>>>(mask, bias_table, qkv_w, proj_w, maskT, relT, wq, wp);
  window_attn<<<B_, 256, 0, stream>>>(x, qkv_b, proj_b, wq, wp, maskT, relT, (float*)d_out, nW);
}